// Round 6
// baseline (91.495 us; speedup 1.0000x reference)
//
#include <hip/hip_runtime.h>
#include <math.h>

#define CN    64
#define NN    1024

// fast tanh via hardware exp2 + rcp: tanh(x) = 1 - 2/(1+e^{2x})
__device__ __forceinline__ float tanh_fast(float x) {
    float e = __expf(2.0f * x);
    return 1.0f - 2.0f * __builtin_amdgcn_rcpf(e + 1.0f);
}

// ---------------------------------------------------------------------------
// prep: per (h,n) U = tanh(pi+b1[h]), V = tanh(pj).
// h-PAIRED layout: S2[hp][n] = float4(U_{2hp}, V_{2hp}, U_{2hp+1}, V_{2hp+1})
// ---------------------------------------------------------------------------
__global__ __launch_bounds__(256) void prep_kernel(
    const float* __restrict__ x, const float* __restrict__ W1,
    const float* __restrict__ b1, float2* __restrict__ S2h)
{
    __shared__ float t_s[2][64];
    const int tid = threadIdx.x;
    const int n0  = blockIdx.x * 2;

    if (tid < 64) {
        float2 xv = *(const float2*)&x[tid * NN + n0];
        t_s[0][tid] = tanh_fast(xv.x);
        t_s[1][tid] = tanh_fast(xv.y);
    }
    __syncthreads();

    const int h  = tid & 127;
    const int nl = tid >> 7;
    const float4* wrow = (const float4*)(W1 + h * (2 * CN));

    float pj[4] = {0.f, 0.f, 0.f, 0.f};
    float pi[4] = {0.f, 0.f, 0.f, 0.f};
#pragma unroll
    for (int c4 = 0; c4 < 16; ++c4) {
        float4 tv = *(const float4*)&t_s[nl][c4 * 4];
        float4 wl = wrow[c4];
        float4 wh = wrow[16 + c4];
        const int s = c4 & 3;
        pj[s] = fmaf(wl.x, tv.x, fmaf(wl.y, tv.y, fmaf(wl.z, tv.z, fmaf(wl.w, tv.w, pj[s]))));
        pi[s] = fmaf(wh.x, tv.x, fmaf(wh.y, tv.y, fmaf(wh.z, tv.z, fmaf(wh.w, tv.w, pi[s]))));
    }
    float pjs = (pj[0] + pj[1]) + (pj[2] + pj[3]);
    float pis = (pi[0] + pi[1]) + (pi[2] + pi[3]);
    float U = tanh_fast(pis + b1[h]);
    float V = tanh_fast(pjs);
    S2h[(((h >> 1) * NN) + n0 + nl) * 2 + (h & 1)] = make_float2(U, V);
}

// ---------------------------------------------------------------------------
// cell: 2-h common-denominator chain, 14 VALU + 1 rcp per cell per 2h.
// ---------------------------------------------------------------------------
__device__ __forceinline__ void cell_term(
    const float4& A, const float4& B,
    float PAe, float QAe, float PAo, float QAo,
    float pBe, float qBe, float pBo, float qBo, float& a)
{
    float d1e = fmaf(A.x, B.y, 1.f);
    float d2e = fmaf(B.x, A.y, 1.f);
    float De  = d1e * d2e;
    float Ne  = fmaf(PAe, qBe, pBe * QAe);
    float d1o = fmaf(A.z, B.w, 1.f);
    float d2o = fmaf(B.z, A.w, 1.f);
    float Do  = d1o * d2o;
    float No  = fmaf(PAo, qBo, pBo * QAo);
    float Num = fmaf(Ne, Do, No * De);
    a = fmaf(Num, __builtin_amdgcn_rcpf(De * Do), a);
}

// Streaming h-loop: fragments straight from global (S is L2-resident, 1 MB),
// manual 1-deep register double-buffer, NO LDS, NO barriers.
template<bool DIAG>
__device__ __forceinline__ void run_stream(
    const float4* __restrict__ pA, const float4* __restrict__ pB,
    const float2* __restrict__ W2p, int hp0, int hpn, float* acc)
{
    float4 An[4], Bn[4];
#pragma unroll
    for (int m = 0; m < 4; ++m) { An[m] = pA[8 * m]; Bn[m] = pB[8 * m]; }

    for (int it = 0; it < hpn; ++it) {
        float4 A[4], B[4];
#pragma unroll
        for (int m = 0; m < 4; ++m) { A[m] = An[m]; B[m] = Bn[m]; }
        if (it + 1 < hpn) {
            pA += NN; pB += NN;
#pragma unroll
            for (int m = 0; m < 4; ++m) { An[m] = pA[8 * m]; Bn[m] = pB[8 * m]; }
        }
        const float2 w2 = W2p[hp0 + it];          // wave-uniform -> s_load
        float PAe[4], QAe[4], PAo[4], QAo[4];
        float pBe[4], qBe[4], pBo[4], qBo[4];
#pragma unroll
        for (int m = 0; m < 4; ++m) {
            PAe[m] = w2.x * (A[m].x + A[m].y);
            QAe[m] = w2.x * fmaf(A[m].x, A[m].y, 1.f);
            PAo[m] = w2.y * (A[m].z + A[m].w);
            QAo[m] = w2.y * fmaf(A[m].z, A[m].w, 1.f);
            pBe[m] = B[m].x + B[m].y;
            qBe[m] = fmaf(B[m].x, B[m].y, 1.f);
            pBo[m] = B[m].z + B[m].w;
            qBo[m] = fmaf(B[m].z, B[m].w, 1.f);
        }
        if (DIAG) {
            int idx = 0;
#pragma unroll
            for (int m = 0; m < 4; ++m)
#pragma unroll
                for (int n = 0; n < 4; ++n)
                    if (n >= m)
                        cell_term(A[m], B[n], PAe[m], QAe[m], PAo[m], QAo[m],
                                  pBe[n], qBe[n], pBo[n], qBo[n], acc[idx++]);
        } else {
#pragma unroll
            for (int m = 0; m < 4; ++m)
#pragma unroll
                for (int n = 0; n < 4; ++n)
                    cell_term(A[m], B[n], PAe[m], QAe[m], PAo[m], QAo[m],
                              pBe[n], qBe[n], pBo[n], qBo[n], acc[m * 4 + n]);
        }
    }
}

// ---------------------------------------------------------------------------
// pair: 512 blocks x 512 threads (8 waves). Blocks 0..15: dual-diagonal
// (tiles 2k,2k+1; upper 10 cell-blocks each; 4 waves/tile x 16 hp).
// Blocks 16..511: off-diag pair, 8 hp per wave. LDS only for the epilogue
// cross-wave reduce (37 KB), no barrier in the main loop.
// ---------------------------------------------------------------------------
__global__ __launch_bounds__(512, 4) void pair_kernel(
    const float4* __restrict__ S2, const float* __restrict__ W2,
    const float* __restrict__ b2, float* __restrict__ out)
{
    const int id  = blockIdx.x;
    const int tid = threadIdx.x;
    const bool dual = (id < 16);

    int i0, j0;
    if (dual) {
        i0 = (2 * id) * 32; j0 = (2 * id + 1) * 32;
    } else {
        int p = id - 16;
        int r = (int)((1.f + sqrtf(8.f * p + 1.f)) * 0.5f);
        while (r * (r - 1) / 2 > p) --r;
        while (r * (r + 1) / 2 <= p) ++r;
        int c = p - r * (r - 1) / 2;
        i0 = c * 32; j0 = r * 32;
    }

    __shared__ float smem[9280];       // 36.25 KB: reduce buf + transpose tile
    const int w = tid >> 6, lane = tid & 63;
    const int la = lane & 7, lb = lane >> 3;
    const float2* W2p = (const float2*)W2;

    float acc[16];
#pragma unroll
    for (int q = 0; q < 16; ++q) acc[q] = 0.f;

    if (dual) {
        const int col = (w < 4) ? i0 : j0;
        const int hp0 = (w & 3) * 16;
        run_stream<true>(S2 + (size_t)hp0 * NN + col + la,
                         S2 + (size_t)hp0 * NN + col + lb,
                         W2p, hp0, 16, acc);
    } else {
        const int hp0 = 8 * w;
        run_stream<false>(S2 + (size_t)hp0 * NN + i0 + la,
                          S2 + (size_t)hp0 * NN + j0 + lb,
                          W2p, hp0, 8, acc);
    }

    float* buf = smem;
    const float bias2 = 2.0f * b2[0];

    if (!dual) {
#pragma unroll
        for (int q = 0; q < 16; ++q)
            buf[w * 1024 + q * 64 + lane] = acc[q];
        __syncthreads();

        float* T = smem + 8192;        // 32x34 floats
        for (int c = tid; c < 1024; c += 512) {
            float v = bias2;
#pragma unroll
            for (int wv = 0; wv < 8; ++wv) v += buf[wv * 1024 + c];
            int q = c >> 6, l2 = c & 63;
            int m = q >> 2, n = q & 3;
            T[((l2 & 7) + 8 * m) * 34 + (l2 >> 3) + 8 * n] = v;
        }
        __syncthreads();

        const int tx = tid & 31, ty = tid >> 5;   // 32x16
        out[(i0 + ty)      * NN + j0 + tx] = T[ty * 34 + tx];
        out[(i0 + ty + 16) * NN + j0 + tx] = T[(ty + 16) * 34 + tx];
        out[(j0 + ty)      * NN + i0 + tx] = T[tx * 34 + ty];
        out[(j0 + ty + 16) * NN + i0 + tx] = T[tx * 34 + ty + 16];
    } else {
#pragma unroll
        for (int q = 0; q < 10; ++q)
            buf[w * 640 + q * 64 + lane] = acc[q];
        __syncthreads();

        float* T0 = smem + 6144;       // 32x34
        float* T1 = smem + 7296;       // 32x34
        for (int c = tid; c < 1280; c += 512) {
            int s = (c >= 640) ? 1 : 0;
            int cc = c - 640 * s;
            float v = bias2;
#pragma unroll
            for (int wv = 0; wv < 4; ++wv) v += buf[(s * 4 + wv) * 640 + cc];
            int qq = cc >> 6, l2 = cc & 63;
            int m = (qq >= 4) + (qq >= 7) + (qq >= 9);
            int start = (m == 0) ? 0 : (m == 1) ? 4 : (m == 2) ? 7 : 9;
            int n = qq - start + m;
            int il = (l2 & 7) + 8 * m, jl = (l2 >> 3) + 8 * n;
            float* T = s ? T1 : T0;
            T[il * 34 + jl] = v;
            if (m != n) T[jl * 34 + il] = v;
        }
        __syncthreads();

        const int tx = tid & 31, ty = tid >> 5;
#pragma unroll
        for (int s = 0; s < 2; ++s) {
            const float* T = s ? T1 : T0;
            const int b0 = s ? j0 : i0;
            out[(b0 + ty)      * NN + b0 + tx] = T[ty * 34 + tx];
            out[(b0 + ty + 16) * NN + b0 + tx] = T[(ty + 16) * 34 + tx];
        }
    }
}

extern "C" void kernel_launch(void* const* d_in, const int* in_sizes, int n_in,
                              void* d_out, int out_size, void* d_ws, size_t ws_size,
                              hipStream_t stream)
{
    const float* x  = (const float*)d_in[0];   // [1,64,1024]
    const float* W1 = (const float*)d_in[1];   // [128,128]
    const float* b1 = (const float*)d_in[2];   // [128]
    const float* W2 = (const float*)d_in[3];   // [128]
    const float* b2 = (const float*)d_in[4];   // [1]
    float* out = (float*)d_out;                // [1,1024,1024] fp32

    float2* S2h = (float2*)d_ws;               // 1 MB: [64 hp][1024 n] float4
    prep_kernel<<<512, 256, 0, stream>>>(x, W1, b1, S2h);
    pair_kernel<<<512, 512, 0, stream>>>((const float4*)d_ws, W2, b2, out);
}

// Round 7
// 91.374 us; speedup vs baseline: 1.0013x; 1.0013x over previous
//
#include <hip/hip_runtime.h>
#include <math.h>

#define CN    64
#define NN    1024

// fast tanh via hardware exp2 + rcp: tanh(x) = 1 - 2/(1+e^{2x})
__device__ __forceinline__ float tanh_fast(float x) {
    float e = __expf(2.0f * x);
    return 1.0f - 2.0f * __builtin_amdgcn_rcpf(e + 1.0f);
}

// ---------------------------------------------------------------------------
// prep: per (h,n) U = tanh(pi+b1[h]), V = tanh(pj).
// h-PAIRED layout: S2[hp][n] = float4(U_{2hp}, V_{2hp}, U_{2hp+1}, V_{2hp+1})
// ---------------------------------------------------------------------------
__global__ __launch_bounds__(256) void prep_kernel(
    const float* __restrict__ x, const float* __restrict__ W1,
    const float* __restrict__ b1, float2* __restrict__ S2h)
{
    __shared__ float t_s[2][64];
    const int tid = threadIdx.x;
    const int n0  = blockIdx.x * 2;

    if (tid < 64) {
        float2 xv = *(const float2*)&x[tid * NN + n0];
        t_s[0][tid] = tanh_fast(xv.x);
        t_s[1][tid] = tanh_fast(xv.y);
    }
    __syncthreads();

    const int h  = tid & 127;
    const int nl = tid >> 7;
    const float4* wrow = (const float4*)(W1 + h * (2 * CN));

    float pj[4] = {0.f, 0.f, 0.f, 0.f};
    float pi[4] = {0.f, 0.f, 0.f, 0.f};
#pragma unroll
    for (int c4 = 0; c4 < 16; ++c4) {
        float4 tv = *(const float4*)&t_s[nl][c4 * 4];
        float4 wl = wrow[c4];
        float4 wh = wrow[16 + c4];
        const int s = c4 & 3;
        pj[s] = fmaf(wl.x, tv.x, fmaf(wl.y, tv.y, fmaf(wl.z, tv.z, fmaf(wl.w, tv.w, pj[s]))));
        pi[s] = fmaf(wh.x, tv.x, fmaf(wh.y, tv.y, fmaf(wh.z, tv.z, fmaf(wh.w, tv.w, pi[s]))));
    }
    float pjs = (pj[0] + pj[1]) + (pj[2] + pj[3]);
    float pis = (pi[0] + pi[1]) + (pi[2] + pi[3]);
    float U = tanh_fast(pis + b1[h]);
    float V = tanh_fast(pjs);
    S2h[(((h >> 1) * NN) + n0 + nl) * 2 + (h & 1)] = make_float2(U, V);
}

// ---------------------------------------------------------------------------
// cell: 2-h common-denominator chain, 14 VALU + 1 rcp per cell per 2h.
// ---------------------------------------------------------------------------
__device__ __forceinline__ void cell_term(
    const float4& A, const float4& B,
    float PAe, float QAe, float PAo, float QAo,
    float pBe, float qBe, float pBo, float qBo, float& a)
{
    float d1e = fmaf(A.x, B.y, 1.f);
    float d2e = fmaf(B.x, A.y, 1.f);
    float De  = d1e * d2e;
    float Ne  = fmaf(PAe, qBe, pBe * QAe);
    float d1o = fmaf(A.z, B.w, 1.f);
    float d2o = fmaf(B.z, A.w, 1.f);
    float Do  = d1o * d2o;
    float No  = fmaf(PAo, qBo, pBo * QAo);
    float Num = fmaf(Ne, Do, No * De);
    a = fmaf(Num, __builtin_amdgcn_rcpf(De * Do), a);
}

// Streaming h-loop from global (S is 1 MB, L2-resident). NO manual prefetch
// double-buffer: the An/Bn copy cost +32 VGPRs and tipped the 128-cap into
// scratch spills (R6). TLP (4 waves/SIMD) hides the ~220cyc L2 latency.
template<bool DIAG>
__device__ __forceinline__ void run_stream(
    const float4* __restrict__ pA, const float4* __restrict__ pB,
    const float2* __restrict__ W2p, int hp0, int hpn, float* acc)
{
#pragma unroll 1
    for (int it = 0; it < hpn; ++it) {
        float4 A[4], B[4];
#pragma unroll
        for (int m = 0; m < 4; ++m) { A[m] = pA[8 * m]; B[m] = pB[8 * m]; }
        pA += NN; pB += NN;

        const float2 w2 = W2p[hp0 + it];          // wave-uniform -> s_load
        float PAe[4], QAe[4], PAo[4], QAo[4];
        float pBe[4], qBe[4], pBo[4], qBo[4];
#pragma unroll
        for (int m = 0; m < 4; ++m) {
            PAe[m] = w2.x * (A[m].x + A[m].y);
            QAe[m] = w2.x * fmaf(A[m].x, A[m].y, 1.f);
            PAo[m] = w2.y * (A[m].z + A[m].w);
            QAo[m] = w2.y * fmaf(A[m].z, A[m].w, 1.f);
            pBe[m] = B[m].x + B[m].y;
            qBe[m] = fmaf(B[m].x, B[m].y, 1.f);
            pBo[m] = B[m].z + B[m].w;
            qBo[m] = fmaf(B[m].z, B[m].w, 1.f);
        }
        if (DIAG) {
            int idx = 0;
#pragma unroll
            for (int m = 0; m < 4; ++m)
#pragma unroll
                for (int n = 0; n < 4; ++n)
                    if (n >= m)
                        cell_term(A[m], B[n], PAe[m], QAe[m], PAo[m], QAo[m],
                                  pBe[n], qBe[n], pBo[n], qBo[n], acc[idx++]);
        } else {
#pragma unroll
            for (int m = 0; m < 4; ++m)
#pragma unroll
                for (int n = 0; n < 4; ++n)
                    cell_term(A[m], B[n], PAe[m], QAe[m], PAo[m], QAo[m],
                              pBe[n], qBe[n], pBo[n], qBo[n], acc[m * 4 + n]);
        }
    }
}

// ---------------------------------------------------------------------------
// pair: 512 blocks x 512 threads (8 waves). Blocks 0..15: dual-diagonal
// (tiles 2k,2k+1; upper 10 cell-blocks each; 4 waves/tile x 16 hp).
// Blocks 16..511: off-diag pair, 8 hp per wave. LDS only for the epilogue
// cross-wave reduce (37 KB), no barrier in the main loop.
// ---------------------------------------------------------------------------
__global__ __launch_bounds__(512, 4) void pair_kernel(
    const float4* __restrict__ S2, const float* __restrict__ W2,
    const float* __restrict__ b2, float* __restrict__ out)
{
    const int id  = blockIdx.x;
    const int tid = threadIdx.x;
    const bool dual = (id < 16);

    int i0, j0;
    if (dual) {
        i0 = (2 * id) * 32; j0 = (2 * id + 1) * 32;
    } else {
        int p = id - 16;
        int r = (int)((1.f + sqrtf(8.f * p + 1.f)) * 0.5f);
        while (r * (r - 1) / 2 > p) --r;
        while (r * (r + 1) / 2 <= p) ++r;
        int c = p - r * (r - 1) / 2;
        i0 = c * 32; j0 = r * 32;
    }

    __shared__ float smem[9280];       // 36.25 KB: reduce buf + transpose tile
    const int w = tid >> 6, lane = tid & 63;
    const int la = lane & 7, lb = lane >> 3;
    const float2* W2p = (const float2*)W2;

    float acc[16];
#pragma unroll
    for (int q = 0; q < 16; ++q) acc[q] = 0.f;

    if (dual) {
        const int col = (w < 4) ? i0 : j0;
        const int hp0 = (w & 3) * 16;
        run_stream<true>(S2 + (size_t)hp0 * NN + col + la,
                         S2 + (size_t)hp0 * NN + col + lb,
                         W2p, hp0, 16, acc);
    } else {
        const int hp0 = 8 * w;
        run_stream<false>(S2 + (size_t)hp0 * NN + i0 + la,
                          S2 + (size_t)hp0 * NN + j0 + lb,
                          W2p, hp0, 8, acc);
    }

    float* buf = smem;
    const float bias2 = 2.0f * b2[0];

    if (!dual) {
#pragma unroll
        for (int q = 0; q < 16; ++q)
            buf[w * 1024 + q * 64 + lane] = acc[q];
        __syncthreads();

        float* T = smem + 8192;        // 32x34 floats
        for (int c = tid; c < 1024; c += 512) {
            float v = bias2;
#pragma unroll
            for (int wv = 0; wv < 8; ++wv) v += buf[wv * 1024 + c];
            int q = c >> 6, l2 = c & 63;
            int m = q >> 2, n = q & 3;
            T[((l2 & 7) + 8 * m) * 34 + (l2 >> 3) + 8 * n] = v;
        }
        __syncthreads();

        const int tx = tid & 31, ty = tid >> 5;   // 32x16
        out[(i0 + ty)      * NN + j0 + tx] = T[ty * 34 + tx];
        out[(i0 + ty + 16) * NN + j0 + tx] = T[(ty + 16) * 34 + tx];
        out[(j0 + ty)      * NN + i0 + tx] = T[tx * 34 + ty];
        out[(j0 + ty + 16) * NN + i0 + tx] = T[tx * 34 + ty + 16];
    } else {
#pragma unroll
        for (int q = 0; q < 10; ++q)
            buf[w * 640 + q * 64 + lane] = acc[q];
        __syncthreads();

        float* T0 = smem + 6144;       // 32x34
        float* T1 = smem + 7296;       // 32x34
        for (int c = tid; c < 1280; c += 512) {
            int s = (c >= 640) ? 1 : 0;
            int cc = c - 640 * s;
            float v = bias2;
#pragma unroll
            for (int wv = 0; wv < 4; ++wv) v += buf[(s * 4 + wv) * 640 + cc];
            int qq = cc >> 6, l2 = cc & 63;
            int m = (qq >= 4) + (qq >= 7) + (qq >= 9);
            int start = (m == 0) ? 0 : (m == 1) ? 4 : (m == 2) ? 7 : 9;
            int n = qq - start + m;
            int il = (l2 & 7) + 8 * m, jl = (l2 >> 3) + 8 * n;
            float* T = s ? T1 : T0;
            T[il * 34 + jl] = v;
            if (m != n) T[jl * 34 + il] = v;
        }
        __syncthreads();

        const int tx = tid & 31, ty = tid >> 5;
#pragma unroll
        for (int s = 0; s < 2; ++s) {
            const float* T = s ? T1 : T0;
            const int b0 = s ? j0 : i0;
            out[(b0 + ty)      * NN + b0 + tx] = T[ty * 34 + tx];
            out[(b0 + ty + 16) * NN + b0 + tx] = T[(ty + 16) * 34 + tx];
        }
    }
}

extern "C" void kernel_launch(void* const* d_in, const int* in_sizes, int n_in,
                              void* d_out, int out_size, void* d_ws, size_t ws_size,
                              hipStream_t stream)
{
    const float* x  = (const float*)d_in[0];   // [1,64,1024]
    const float* W1 = (const float*)d_in[1];   // [128,128]
    const float* b1 = (const float*)d_in[2];   // [128]
    const float* W2 = (const float*)d_in[3];   // [128]
    const float* b2 = (const float*)d_in[4];   // [1]
    float* out = (float*)d_out;                // [1,1024,1024] fp32

    float2* S2h = (float2*)d_ws;               // 1 MB: [64 hp][1024 n] float4
    prep_kernel<<<512, 256, 0, stream>>>(x, W1, b1, S2h);
    pair_kernel<<<512, 512, 0, stream>>>((const float4*)d_ws, W2, b2, out);
}